// Round 2
// baseline (325.609 us; speedup 1.0000x reference)
//
#include <hip/hip_runtime.h>
#include <stdint.h>

typedef unsigned short u16;
typedef __attribute__((ext_vector_type(8))) short short8;
typedef __attribute__((ext_vector_type(4))) float f32x4;
typedef __attribute__((ext_vector_type(4))) unsigned short u16x4;
typedef __attribute__((ext_vector_type(4))) unsigned int uint4v;

#define MFMA16(a,b,c) __builtin_amdgcn_mfma_f32_16x16x32_bf16((a),(b),(c),0,0,0)

__device__ __forceinline__ void gload16(const void* g, void* l) {
  __builtin_amdgcn_global_load_lds(
      (__attribute__((address_space(1))) void*)(uintptr_t)(g),
      (__attribute__((address_space(3))) void*)(uint32_t)(uintptr_t)(l),
      16, 0, 0);
}

__device__ __forceinline__ u16 f2bf(float x) {
  union { float f; unsigned u; } v; v.f = x;
  unsigned r = v.u + 0x7fffu + ((v.u >> 16) & 1u);
  return (u16)(r >> 16);
}
__device__ __forceinline__ unsigned pack2(float a, float b) {
  return (unsigned)f2bf(a) | ((unsigned)f2bf(b) << 16);
}

// ---------------- cast fp32 -> bf16 for the three inputs ----------------
__global__ __launch_bounds__(256) void cast_x(const float* x0, const float* x1, const float* x2,
                                              u16* y0, u16* y1, u16* y2) {
  const float* x; u16* y;
  if (blockIdx.y == 0)      { x = x0; y = y0; }
  else if (blockIdx.y == 1) { x = x1; y = y1; }
  else                      { x = x2; y = y2; }
  size_t i = ((size_t)blockIdx.x * 256 + threadIdx.x) * 4;
  float4 v = *(const float4*)(x + i);
  u16x4 o; o[0] = f2bf(v.x); o[1] = f2bf(v.y); o[2] = f2bf(v.z); o[3] = f2bf(v.w);
  *(u16x4*)(y + i) = o;
}

// ---------------- transpose + cast weights: WT[n][k] = bf16(W[k][n]) ----------------
__global__ __launch_bounds__(256) void trans_w(const float* w0, const float* w1, const float* w2, const float* w3,
                                               u16* t0, u16* t1, u16* t2, u16* t3) {
  const float* W; u16* T;
  switch (blockIdx.z) {
    case 0:  W = w0; T = t0; break;
    case 1:  W = w1; T = t1; break;
    case 2:  W = w2; T = t2; break;
    default: W = w3; T = t3; break;
  }
  __shared__ float tile[32][33];
  int k0 = blockIdx.x * 32, n0 = blockIdx.y * 32;
  int tx = threadIdx.x, ty = threadIdx.y;
#pragma unroll
  for (int j = 0; j < 4; ++j)
    tile[ty + 8*j][tx] = W[(size_t)(k0 + ty + 8*j) * 1024 + n0 + tx];
  __syncthreads();
#pragma unroll
  for (int j = 0; j < 4; ++j)
    T[(size_t)(n0 + ty + 8*j) * 1024 + k0 + tx] = f2bf(tile[tx][ty + 8*j]);
}

// ---------------- shared GEMM core: C[128x128] = A[4096x1024] * WT^T, bf16 MFMA ----------------
__device__ __forceinline__ void gemm_stage(const u16* A, const u16* BT, int row0, int col0,
                                           int tid, int w, int kt, char* la, char* lb) {
#pragma unroll
  for (int j = 0; j < 2; ++j) {
    int c = j * 256 + tid;
    int mr = c & 127, kc = c >> 7;
    gload16(A  + (size_t)(row0 + mr) * 1024 + kt*32 + kc*8, la + (j*4 + w) * 1024);
    gload16(BT + (size_t)(col0 + mr) * 1024 + kt*32 + kc*8, lb + (j*4 + w) * 1024);
  }
}

__device__ __forceinline__ void gemm_core(const u16* A, const u16* BT, int row0, int col0,
                                          char* ldsA, char* ldsB, f32x4 (&acc)[4][4]) {
  int tid = threadIdx.x, w = tid >> 6, lane = tid & 63;
  int u = lane >> 4, c16 = lane & 15, wr = w >> 1, wc = w & 1;
  gemm_stage(A, BT, row0, col0, tid, w, 0, ldsA, ldsB);
  asm volatile("s_waitcnt vmcnt(0)" ::: "memory");
  __syncthreads();
  for (int kt = 0; kt < 32; ++kt) {
    int cur = kt & 1;
    if (kt < 31)
      gemm_stage(A, BT, row0, col0, tid, w, kt + 1, ldsA + (cur^1)*8192, ldsB + (cur^1)*8192);
    const char* la = ldsA + cur * 8192;
    const char* lb = ldsB + cur * 8192;
    short8 af[4], bv[4];
#pragma unroll
    for (int i = 0; i < 4; ++i) {
      af[i] = *(const short8*)(la + (u*128 + wr*64 + i*16 + c16) * 16);
      bv[i] = *(const short8*)(lb + (u*128 + wc*64 + i*16 + c16) * 16);
    }
#pragma unroll
    for (int i = 0; i < 4; ++i)
#pragma unroll
      for (int n = 0; n < 4; ++n)
        acc[i][n] = MFMA16(af[i], bv[n], acc[i][n]);
    asm volatile("s_waitcnt vmcnt(0)" ::: "memory");
    __syncthreads();
  }
}

// ---------------- QKV projections ----------------
__global__ __launch_bounds__(256) void gemm_qkv(const u16* Xq, const u16* Xk, const u16* Xv,
                                                const u16* WTq, const u16* WTk, const u16* WTv,
                                                u16* Qh, u16* Kh, u16* VhT) {
  __shared__ char ldsA[16384], ldsB[16384];
  int z = blockIdx.z;
  const u16* A  = (z == 0) ? Xq  : ((z == 1) ? Xk  : Xv);
  const u16* BT = (z == 0) ? WTq : ((z == 1) ? WTk : WTv);
  int row0 = blockIdx.x * 128, col0 = blockIdx.y * 128;
  f32x4 acc[4][4] = {};
  gemm_core(A, BT, row0, col0, ldsA, ldsB, acc);
  int tid = threadIdx.x, w = tid >> 6, lane = tid & 63, u = lane >> 4, c16 = lane & 15;
  int wr = w >> 1, wc = w & 1;
#pragma unroll
  for (int i = 0; i < 4; ++i)
#pragma unroll
    for (int n = 0; n < 4; ++n)
#pragma unroll
      for (int r = 0; r < 4; ++r) {
        int row = row0 + wr*64 + i*16 + u*4 + r;
        int colg = col0 + wc*64 + n*16 + c16;
        int b = row >> 11, s = row & 2047;
        int h = colg >> 6, d = colg & 63;
        float v = acc[i][n][r];
        if (z == 0)      Qh[((size_t)(b*16 + h) * 2048 + s) * 64 + d] = f2bf(v * 0.125f);
        else if (z == 1) Kh[((size_t)(b*16 + h) * 2048 + s) * 64 + d] = f2bf(v);
        else             VhT[((size_t)(b*16 + h) * 64 + d) * 2048 + s] = f2bf(v);
      }
}

// ---------------- output projection + residual ----------------
__global__ __launch_bounds__(256) void gemm_out(const u16* Ctx, const u16* WTo,
                                                const float* resid, float* outF) {
  __shared__ char ldsA[16384], ldsB[16384];
  int row0 = blockIdx.x * 128, col0 = blockIdx.y * 128;
  f32x4 acc[4][4] = {};
  gemm_core(Ctx, WTo, row0, col0, ldsA, ldsB, acc);
  int tid = threadIdx.x, w = tid >> 6, lane = tid & 63, u = lane >> 4, c16 = lane & 15;
  int wr = w >> 1, wc = w & 1;
#pragma unroll
  for (int i = 0; i < 4; ++i)
#pragma unroll
    for (int n = 0; n < 4; ++n)
#pragma unroll
      for (int r = 0; r < 4; ++r) {
        int row = row0 + wr*64 + i*16 + u*4 + r;
        int colg = col0 + wc*64 + n*16 + c16;
        size_t idx = (size_t)row * 1024 + colg;
        outF[idx] = acc[i][n][r] + resid[idx];
      }
}

// ---------------- fused causal attention ----------------
__device__ __forceinline__ void qk_tile(const char* Kbuf, short8 qf0, short8 qf1,
                                        int cq, int u, int rho, f32x4 (&acc)[4]) {
#pragma unroll
  for (int st = 0; st < 4; ++st) {
    short8 a0 = *(const short8*)(Kbuf + (st*16 + cq) * 128 + ((u*16) ^ rho));
    short8 a1 = *(const short8*)(Kbuf + (st*16 + cq) * 128 + ((64 + u*16) ^ rho));
    acc[st] = MFMA16(a0, qf0, acc[st]);
    acc[st] = MFMA16(a1, qf1, acc[st]);
  }
}

__device__ __forceinline__ void stage_k64(const u16* pan, int kt, char* buf, int tid, int w) {
#pragma unroll
  for (int j = 0; j < 2; ++j) {
    int c = j * 256 + tid;
    int row = c >> 3;
    int cc = (c & 7) ^ (row & 7);
    gload16(pan + (size_t)(kt*64 + row) * 64 + cc*8, buf + (j*4 + w) * 1024);
  }
}
__device__ __forceinline__ void stage_v64(const u16* vpan, int kt, char* buf, int tid, int w) {
#pragma unroll
  for (int j = 0; j < 2; ++j) {
    int c = j * 256 + tid;
    int d = c >> 3;
    int cc = (c & 7) ^ (d & 7);
    gload16(vpan + (size_t)d * 2048 + kt*64 + cc*8, buf + (j*4 + w) * 1024);
  }
}

__global__ __launch_bounds__(256) void attn_fused(const u16* Qh, const u16* Kh, const u16* VhT,
                                                  float* attnO, u16* Ctx) {
  __shared__ char Kl[2][8192];
  __shared__ char Vl[2][8192];
  __shared__ float Pf[4][1024];     // per-wave 16 q-rows x 64 keys, XOR-swizzled words
  int tid = threadIdx.x, w = tid >> 6, lane = tid & 63;
  int u = lane >> 4, cq = lane & 15;
  int q0 = blockIdx.x * 64, bh = blockIdx.y;
  int q = q0 + w*16 + cq;
  int rho = (cq & 7) << 4;          // byte xor for K/V tiles
  int sw  = (cq & 7) << 2;          // word xor for Pf rows (row == cq)
  const u16* Kpan = Kh  + (size_t)bh * (2048 * 64);
  const u16* Vpan = VhT + (size_t)bh * (64 * 2048);
  const u16* Qrow = Qh  + ((size_t)bh * 2048 + q) * 64;
  short8 qf0 = *(const short8*)(Qrow + u*8);
  short8 qf1 = *(const short8*)(Qrow + 32 + u*8);
  int ktd = q0 >> 6;                // inclusive diagonal tile index

  // ---- pass 1: row sum of exp(S) with fixed max 0 (scores are O(1) by construction) ----
  float ls = 0.f;
  stage_k64(Kpan, 0, Kl[0], tid, w);
  asm volatile("s_waitcnt vmcnt(0)" ::: "memory");
  __syncthreads();
  for (int kt = 0; kt <= ktd; ++kt) {
    int cur = kt & 1;
    if (kt < ktd) stage_k64(Kpan, kt + 1, Kl[cur ^ 1], tid, w);
    f32x4 acc[4] = {};
    qk_tile(Kl[cur], qf0, qf1, cq, u, rho, acc);
    if (kt == ktd) {
#pragma unroll
      for (int st = 0; st < 4; ++st)
#pragma unroll
        for (int r = 0; r < 4; ++r) {
          int key = q0 + st*16 + u*4 + r;
          if (key > q) acc[st][r] = -1e30f;   // expf underflows to exact 0
        }
    }
#pragma unroll
    for (int st = 0; st < 4; ++st)
#pragma unroll
      for (int r = 0; r < 4; ++r) ls += __expf(acc[st][r]);
    asm volatile("s_waitcnt vmcnt(0)" ::: "memory");
    __syncthreads();
  }
  ls += __shfl_xor(ls, 16);
  ls += __shfl_xor(ls, 32);
  float rl = 1.f / ls;

  // ---- pass 2: recompute S, write coalesced probs via LDS transpose, ctx = P*V ----
  f32x4 ctx[4] = {};
  float* apan = attnO + (size_t)bh * 2048 * 2048;
  float* Pw = Pf[w];
  stage_k64(Kpan, 0, Kl[0], tid, w);
  stage_v64(Vpan, 0, Vl[0], tid, w);
  asm volatile("s_waitcnt vmcnt(0)" ::: "memory");
  __syncthreads();
  for (int kt = 0; kt <= ktd; ++kt) {
    int cur = kt & 1;
    if (kt < ktd) {
      stage_k64(Kpan, kt + 1, Kl[cur ^ 1], tid, w);
      stage_v64(Vpan, kt + 1, Vl[cur ^ 1], tid, w);
    }
    f32x4 acc[4] = {};
    qk_tile(Kl[cur], qf0, qf1, cq, u, rho, acc);
    if (kt == ktd) {
#pragma unroll
      for (int st = 0; st < 4; ++st)
#pragma unroll
        for (int r = 0; r < 4; ++r) {
          int key = q0 + st*16 + u*4 + r;
          if (key > q) acc[st][r] = -1e30f;
        }
    }
    // normalized probs -> per-wave LDS (row = cq, 64 keys f32, word-swizzled)
#pragma unroll
    for (int st = 0; st < 4; ++st) {
      f32x4 p;
#pragma unroll
      for (int r = 0; r < 4; ++r) p[r] = __expf(acc[st][r]) * rl;
      *(f32x4*)&Pw[(cq*64 + st*16 + u*4) ^ sw] = p;
    }
    __builtin_amdgcn_sched_barrier(0);
    // coalesced store: 4 instrs x (4 rows x 256B contiguous)
#pragma unroll
    for (int j = 0; j < 4; ++j) {
      int row = j*4 + u;
      int pos = lane & 15;
      f32x4 v = *(const f32x4*)&Pw[(row*64 + pos*4) ^ ((row & 7) << 2)];
      *(f32x4*)(apan + (size_t)(q0 + w*16 + row) * 2048 + kt*64 + pos*4) = v;
    }
    // PV: A-fragments re-read from Pf (own row cq), packed to bf16 in-register
#pragma unroll
    for (int wd = 0; wd < 2; ++wd) {
      int b0 = (cq*64 + wd*32 + u*8) ^ sw;
      f32x4 pa0 = *(const f32x4*)&Pw[b0];
      f32x4 pa1 = *(const f32x4*)&Pw[b0 ^ 4];
      uint4v pk;
      pk[0] = pack2(pa0[0], pa0[1]);
      pk[1] = pack2(pa0[2], pa0[3]);
      pk[2] = pack2(pa1[0], pa1[1]);
      pk[3] = pack2(pa1[2], pa1[3]);
      union { uint4v u4; short8 s8; } cvt; cvt.u4 = pk;
      short8 pa = cvt.s8;
#pragma unroll
      for (int nt = 0; nt < 4; ++nt) {
        short8 vb = *(const short8*)(Vl[cur] + (nt*16 + cq) * 128 + ((wd*64 + u*16) ^ rho));
        ctx[nt] = MFMA16(pa, vb, ctx[nt]);
      }
    }
    asm volatile("s_waitcnt vmcnt(0)" ::: "memory");
    __syncthreads();
  }

  // masked tail: exact zeros, coalesced 4 rows x 256B per instr
  f32x4 z4 = {};
  for (int kt = ktd + 1; kt < 32; ++kt) {
#pragma unroll
    for (int j = 0; j < 4; ++j)
      *(f32x4*)(apan + (size_t)(q0 + w*16 + j*4 + u) * 2048 + kt*64 + (lane & 15)*4) = z4;
  }

  // ctx write: [BS][1024] bf16 for the output GEMM
  int b = bh >> 4, h = bh & 15;
#pragma unroll
  for (int nt = 0; nt < 4; ++nt)
#pragma unroll
    for (int r = 0; r < 4; ++r) {
      int qr = q0 + w*16 + u*4 + r;
      Ctx[((size_t)b * 2048 + qr) * 1024 + h*64 + nt*16 + cq] = f2bf(ctx[nt][r]);
    }
}

// ---------------- LayerNorm over 1024 cols ----------------
__global__ __launch_bounds__(256) void ln_kernel(const float* X, const float* g, const float* b, float* out) {
  int row = blockIdx.x, tid = threadIdx.x;
  float4 v = *(const float4*)(X + (size_t)row * 1024 + tid * 4);
  float s  = v.x + v.y + v.z + v.w;
  float q2 = v.x*v.x + v.y*v.y + v.z*v.z + v.w*v.w;
#pragma unroll
  for (int off = 32; off; off >>= 1) { s += __shfl_xor(s, off); q2 += __shfl_xor(q2, off); }
  __shared__ float red[8];
  int w = tid >> 6, lane = tid & 63;
  if (lane == 0) { red[w] = s; red[4 + w] = q2; }
  __syncthreads();
  s  = red[0] + red[1] + red[2] + red[3];
  q2 = red[4] + red[5] + red[6] + red[7];
  float mean = s * (1.f / 1024.f);
  float var  = q2 * (1.f / 1024.f) - mean * mean;
  float rs   = rsqrtf(var + 1e-5f);
  float4 gv = *(const float4*)(g + tid * 4);
  float4 bv = *(const float4*)(b + tid * 4);
  float4 o;
  o.x = (v.x - mean) * rs * gv.x + bv.x;
  o.y = (v.y - mean) * rs * gv.y + bv.y;
  o.z = (v.z - mean) * rs * gv.z + bv.z;
  o.w = (v.w - mean) * rs * gv.w + bv.w;
  *(float4*)(out + (size_t)row * 1024 + tid * 4) = o;
}

extern "C" void kernel_launch(void* const* d_in, const int* in_sizes, int n_in,
                              void* d_out, int out_size, void* d_ws, size_t ws_size,
                              hipStream_t stream) {
  (void)in_sizes; (void)n_in; (void)out_size; (void)ws_size;
  const float* inQ = (const float*)d_in[0];
  const float* inK = (const float*)d_in[1];
  const float* inV = (const float*)d_in[2];
  const float* Wq  = (const float*)d_in[4];
  const float* Wk  = (const float*)d_in[5];
  const float* Wv  = (const float*)d_in[6];
  const float* Wo  = (const float*)d_in[7];
  const float* gam = (const float*)d_in[8];
  const float* bet = (const float*)d_in[9];
  float* out   = (float*)d_out;
  float* attnO = out + (size_t)4194304;

  char* ws = (char*)d_ws;
  u16*   WTo    = (u16*)ws;
  u16*   Qh     = (u16*)(ws + 2097152);
  u16*   Kh     = (u16*)(ws + 2097152 + (size_t)8388608);
  u16*   VhT    = (u16*)(ws + 2097152 + (size_t)2*8388608);
  u16*   Ctx    = (u16*)(ws + 2097152 + (size_t)3*8388608);
  float* OutLin = (float*)(ws + 2097152 + (size_t)4*8388608);

  u16* Xbq = (u16*)attnO;
  u16* Xbk = Xbq + (size_t)4194304;
  u16* Xbv = Xbk + (size_t)4194304;
  u16* WTq = Xbv + (size_t)4194304;
  u16* WTk = WTq + (size_t)1048576;
  u16* WTv = WTk + (size_t)1048576;

  cast_x<<<dim3(4096, 3), 256, 0, stream>>>(inQ, inK, inV, Xbq, Xbk, Xbv);
  trans_w<<<dim3(32, 32, 4), dim3(32, 8), 0, stream>>>(Wq, Wk, Wv, Wo, WTq, WTk, WTv, WTo);
  gemm_qkv<<<dim3(32, 8, 3), 256, 0, stream>>>(Xbq, Xbk, Xbv, WTq, WTk, WTv, Qh, Kh, VhT);
  attn_fused<<<dim3(32, 32), 256, 0, stream>>>(Qh, Kh, VhT, attnO, Ctx);
  gemm_out<<<dim3(32, 8), 256, 0, stream>>>(Ctx, WTo, inQ, OutLin);
  ln_kernel<<<4096, 256, 0, stream>>>(OutLin, gam, bet, out);
}

// Round 3
// 289.096 us; speedup vs baseline: 1.1263x; 1.1263x over previous
//
#include <hip/hip_runtime.h>
#include <stdint.h>

typedef unsigned short u16;
typedef __attribute__((ext_vector_type(8))) short short8;
typedef __attribute__((ext_vector_type(4))) float f32x4;
typedef __attribute__((ext_vector_type(4))) unsigned short u16x4;
typedef __attribute__((ext_vector_type(4))) unsigned int uint4v;

#define MFMA16(a,b,c) __builtin_amdgcn_mfma_f32_16x16x32_bf16((a),(b),(c),0,0,0)

__device__ __forceinline__ void gload16(const void* g, void* l) {
  __builtin_amdgcn_global_load_lds(
      (__attribute__((address_space(1))) void*)(uintptr_t)(g),
      (__attribute__((address_space(3))) void*)(uint32_t)(uintptr_t)(l),
      16, 0, 0);
}

__device__ __forceinline__ u16 f2bf(float x) {
  union { float f; unsigned u; } v; v.f = x;
  unsigned r = v.u + 0x7fffu + ((v.u >> 16) & 1u);
  return (u16)(r >> 16);
}
__device__ __forceinline__ unsigned pack2(float a, float b) {
  return (unsigned)f2bf(a) | ((unsigned)f2bf(b) << 16);
}

// ---------------- cast fp32 -> bf16 for the three inputs ----------------
__global__ __launch_bounds__(256) void cast_x(const float* x0, const float* x1, const float* x2,
                                              u16* y0, u16* y1, u16* y2) {
  const float* x; u16* y;
  if (blockIdx.y == 0)      { x = x0; y = y0; }
  else if (blockIdx.y == 1) { x = x1; y = y1; }
  else                      { x = x2; y = y2; }
  size_t i = ((size_t)blockIdx.x * 256 + threadIdx.x) * 4;
  float4 v = *(const float4*)(x + i);
  u16x4 o; o[0] = f2bf(v.x); o[1] = f2bf(v.y); o[2] = f2bf(v.z); o[3] = f2bf(v.w);
  *(u16x4*)(y + i) = o;
}

// ---------------- transpose + cast weights: WT[n][k] = bf16(W[k][n]) ----------------
__global__ __launch_bounds__(256) void trans_w(const float* w0, const float* w1, const float* w2, const float* w3,
                                               u16* t0, u16* t1, u16* t2, u16* t3) {
  const float* W; u16* T;
  switch (blockIdx.z) {
    case 0:  W = w0; T = t0; break;
    case 1:  W = w1; T = t1; break;
    case 2:  W = w2; T = t2; break;
    default: W = w3; T = t3; break;
  }
  __shared__ float tile[32][33];
  int k0 = blockIdx.x * 32, n0 = blockIdx.y * 32;
  int tx = threadIdx.x, ty = threadIdx.y;
#pragma unroll
  for (int j = 0; j < 4; ++j)
    tile[ty + 8*j][tx] = W[(size_t)(k0 + ty + 8*j) * 1024 + n0 + tx];
  __syncthreads();
#pragma unroll
  for (int j = 0; j < 4; ++j)
    T[(size_t)(n0 + ty + 8*j) * 1024 + k0 + tx] = f2bf(tile[tx][ty + 8*j]);
}

// ---------------- shared GEMM core: C[128x128] = A * WT^T, bf16 MFMA ----------------
__device__ __forceinline__ void gemm_stage(const u16* A, const u16* BT, int row0, int col0,
                                           int tid, int w, int kt, char* la, char* lb) {
#pragma unroll
  for (int j = 0; j < 2; ++j) {
    int c = j * 256 + tid;
    int mr = c & 127, kc = c >> 7;
    gload16(A  + (size_t)(row0 + mr) * 1024 + kt*32 + kc*8, la + (j*4 + w) * 1024);
    gload16(BT + (size_t)(col0 + mr) * 1024 + kt*32 + kc*8, lb + (j*4 + w) * 1024);
  }
}

__device__ __forceinline__ void gemm_core(const u16* A, const u16* BT, int row0, int col0,
                                          char* ldsA, char* ldsB, f32x4 (&acc)[4][4]) {
  int tid = threadIdx.x, w = tid >> 6, lane = tid & 63;
  int u = lane >> 4, c16 = lane & 15, wr = w >> 1, wc = w & 1;
  gemm_stage(A, BT, row0, col0, tid, w, 0, ldsA, ldsB);
  asm volatile("s_waitcnt vmcnt(0)" ::: "memory");
  __syncthreads();
  for (int kt = 0; kt < 32; ++kt) {
    int cur = kt & 1;
    if (kt < 31)
      gemm_stage(A, BT, row0, col0, tid, w, kt + 1, ldsA + (cur^1)*8192, ldsB + (cur^1)*8192);
    const char* la = ldsA + cur * 8192;
    const char* lb = ldsB + cur * 8192;
    short8 af[4], bv[4];
#pragma unroll
    for (int i = 0; i < 4; ++i) {
      af[i] = *(const short8*)(la + (u*128 + wr*64 + i*16 + c16) * 16);
      bv[i] = *(const short8*)(lb + (u*128 + wc*64 + i*16 + c16) * 16);
    }
#pragma unroll
    for (int i = 0; i < 4; ++i)
#pragma unroll
      for (int n = 0; n < 4; ++n)
        acc[i][n] = MFMA16(af[i], bv[n], acc[i][n]);
    asm volatile("s_waitcnt vmcnt(0)" ::: "memory");
    __syncthreads();
  }
}

// ---------------- QKV projections ----------------
__global__ __launch_bounds__(256) void gemm_qkv(const u16* Xq, const u16* Xk, const u16* Xv,
                                                const u16* WTq, const u16* WTk, const u16* WTv,
                                                u16* Qh, u16* Kh, u16* VhT) {
  __shared__ char ldsA[16384], ldsB[16384];
  int z = blockIdx.z;
  const u16* A  = (z == 0) ? Xq  : ((z == 1) ? Xk  : Xv);
  const u16* BT = (z == 0) ? WTq : ((z == 1) ? WTk : WTv);
  int row0 = blockIdx.x * 128, col0 = blockIdx.y * 128;
  f32x4 acc[4][4] = {};
  gemm_core(A, BT, row0, col0, ldsA, ldsB, acc);
  int tid = threadIdx.x, w = tid >> 6, lane = tid & 63, u = lane >> 4, c16 = lane & 15;
  int wr = w >> 1, wc = w & 1;
#pragma unroll
  for (int i = 0; i < 4; ++i)
#pragma unroll
    for (int n = 0; n < 4; ++n)
#pragma unroll
      for (int r = 0; r < 4; ++r) {
        int row = row0 + wr*64 + i*16 + u*4 + r;
        int colg = col0 + wc*64 + n*16 + c16;
        int b = row >> 11, s = row & 2047;
        int h = colg >> 6, d = colg & 63;
        float v = acc[i][n][r];
        if (z == 0)      Qh[((size_t)(b*16 + h) * 2048 + s) * 64 + d] = f2bf(v * 0.125f);
        else if (z == 1) Kh[((size_t)(b*16 + h) * 2048 + s) * 64 + d] = f2bf(v);
        else             VhT[((size_t)(b*16 + h) * 64 + d) * 2048 + s] = f2bf(v);
      }
}

// ---------------- output projection + residual ----------------
__global__ __launch_bounds__(256) void gemm_out(const u16* Ctx, const u16* WTo,
                                                const float* resid, float* outF) {
  __shared__ char ldsA[16384], ldsB[16384];
  int row0 = blockIdx.x * 128, col0 = blockIdx.y * 128;
  f32x4 acc[4][4] = {};
  gemm_core(Ctx, WTo, row0, col0, ldsA, ldsB, acc);
  int tid = threadIdx.x, w = tid >> 6, lane = tid & 63, u = lane >> 4, c16 = lane & 15;
  int wr = w >> 1, wc = w & 1;
#pragma unroll
  for (int i = 0; i < 4; ++i)
#pragma unroll
    for (int n = 0; n < 4; ++n)
#pragma unroll
      for (int r = 0; r < 4; ++r) {
        int row = row0 + wr*64 + i*16 + u*4 + r;
        int colg = col0 + wc*64 + n*16 + c16;
        size_t idx = (size_t)row * 1024 + colg;
        outF[idx] = acc[i][n][r] + resid[idx];
      }
}

// ---------------- fused causal attention (pair-balanced) ----------------
__device__ __forceinline__ void qk_tile(const char* Kbuf, short8 qf0, short8 qf1,
                                        int cq, int u, int rho, f32x4 (&acc)[4]) {
#pragma unroll
  for (int st = 0; st < 4; ++st) {
    short8 a0 = *(const short8*)(Kbuf + (st*16 + cq) * 128 + ((u*16) ^ rho));
    short8 a1 = *(const short8*)(Kbuf + (st*16 + cq) * 128 + ((64 + u*16) ^ rho));
    acc[st] = MFMA16(a0, qf0, acc[st]);
    acc[st] = MFMA16(a1, qf1, acc[st]);
  }
}

__device__ __forceinline__ void stage_k64(const u16* pan, int kt, char* buf, int tid, int w) {
#pragma unroll
  for (int j = 0; j < 2; ++j) {
    int c = j * 256 + tid;
    int row = c >> 3;
    int cc = (c & 7) ^ (row & 7);
    gload16(pan + (size_t)(kt*64 + row) * 64 + cc*8, buf + (j*4 + w) * 1024);
  }
}
__device__ __forceinline__ void stage_v64(const u16* vpan, int kt, char* buf, int tid, int w) {
#pragma unroll
  for (int j = 0; j < 2; ++j) {
    int c = j * 256 + tid;
    int d = c >> 3;
    int cc = (c & 7) ^ (d & 7);
    gload16(vpan + (size_t)d * 2048 + kt*64 + cc*8, buf + (j*4 + w) * 1024);
  }
}

// pass-1 tile: accumulate sum of exp(S) for one q-tile
__device__ __forceinline__ void tile_pass1(const char* Kcur, short8 qf0, short8 qf1,
                                           int q, int q0t, int kt, int ktd_t,
                                           int cq, int u, int rho, float& ls) {
  f32x4 acc[4] = {};
  qk_tile(Kcur, qf0, qf1, cq, u, rho, acc);
  if (kt == ktd_t) {
#pragma unroll
    for (int st = 0; st < 4; ++st)
#pragma unroll
      for (int r = 0; r < 4; ++r) {
        int key = q0t + st*16 + u*4 + r;
        if (key > q) acc[st][r] = -1e30f;
      }
  }
#pragma unroll
  for (int st = 0; st < 4; ++st)
#pragma unroll
    for (int r = 0; r < 4; ++r) ls += __expf(acc[st][r]);
}

// pass-2 tile: probs -> LDS transpose -> coalesced global store; ctx += P*V
__device__ __forceinline__ void tile_pass2(const char* Kcur, const char* Vcur, float* Pw,
                                           short8 qf0, short8 qf1, int q, int q0t, int kt, int ktd_t,
                                           float rl, float* apan, int w, int u, int cq,
                                           int rho, int sw, f32x4 (&ctx)[4]) {
  f32x4 acc[4] = {};
  qk_tile(Kcur, qf0, qf1, cq, u, rho, acc);
  if (kt == ktd_t) {
#pragma unroll
    for (int st = 0; st < 4; ++st)
#pragma unroll
      for (int r = 0; r < 4; ++r) {
        int key = q0t + st*16 + u*4 + r;
        if (key > q) acc[st][r] = -1e30f;
      }
  }
#pragma unroll
  for (int st = 0; st < 4; ++st) {
    f32x4 p;
#pragma unroll
    for (int r = 0; r < 4; ++r) p[r] = __expf(acc[st][r]) * rl;
    *(f32x4*)&Pw[(cq*64 + st*16 + u*4) ^ sw] = p;
  }
  __builtin_amdgcn_sched_barrier(0);
#pragma unroll
  for (int j = 0; j < 4; ++j) {
    int row = j*4 + u;
    f32x4 v = *(const f32x4*)&Pw[(row*64 + cq*4) ^ ((row & 7) << 2)];
    *(f32x4*)(apan + (size_t)(q0t + w*16 + row) * 2048 + kt*64 + cq*4) = v;
  }
#pragma unroll
  for (int wd = 0; wd < 2; ++wd) {
    int b0 = (cq*64 + wd*32 + u*8) ^ sw;
    f32x4 pa0 = *(const f32x4*)&Pw[b0];
    f32x4 pa1 = *(const f32x4*)&Pw[b0 ^ 4];
    uint4v pk;
    pk[0] = pack2(pa0[0], pa0[1]);
    pk[1] = pack2(pa0[2], pa0[3]);
    pk[2] = pack2(pa1[0], pa1[1]);
    pk[3] = pack2(pa1[2], pa1[3]);
    union { uint4v u4; short8 s8; } cvt; cvt.u4 = pk;
    short8 pa = cvt.s8;
#pragma unroll
    for (int nt = 0; nt < 4; ++nt) {
      short8 vb = *(const short8*)(Vcur + (nt*16 + cq) * 128 + ((wd*64 + u*16) ^ rho));
      ctx[nt] = MFMA16(pa, vb, ctx[nt]);
    }
  }
  __builtin_amdgcn_sched_barrier(0);
}

__global__ __launch_bounds__(256) void attn_fused(const u16* Qh, const u16* Kh, const u16* VhT,
                                                  float* attnO, u16* Ctx) {
  __shared__ char Kl[2][8192];
  __shared__ char Vl[2][8192];
  __shared__ float Pf[4][1024];     // per-wave 16 q-rows x 64 keys f32, XOR-swizzled words
  int tid = threadIdx.x, w = tid >> 6, lane = tid & 63;
  int u = lane >> 4, cq = lane & 15;
  int pi = blockIdx.x;              // pair index 0..15: tiles pi (lo) and 31-pi (hi)
  int bh = blockIdx.y;
  int tlo = pi, thi = 31 - pi;
  int q0lo = tlo * 64, q0hi = thi * 64;
  int qlo = q0lo + w*16 + cq;
  int qhi = q0hi + w*16 + cq;
  int rho = (cq & 7) << 4;
  int sw  = (cq & 7) << 2;
  const u16* Kpan = Kh  + (size_t)bh * (2048 * 64);
  const u16* Vpan = VhT + (size_t)bh * (64 * 2048);
  const u16* Qlo = Qh + ((size_t)bh * 2048 + qlo) * 64;
  const u16* Qhi = Qh + ((size_t)bh * 2048 + qhi) * 64;
  short8 qlo0 = *(const short8*)(Qlo + u*8);
  short8 qlo1 = *(const short8*)(Qlo + 32 + u*8);
  short8 qhi0 = *(const short8*)(Qhi + u*8);
  short8 qhi1 = *(const short8*)(Qhi + 32 + u*8);

  // ---- pass 1: row sums of exp(S), both tiles share K staging ----
  float ls_lo = 0.f, ls_hi = 0.f;
  stage_k64(Kpan, 0, Kl[0], tid, w);
  asm volatile("s_waitcnt vmcnt(0)" ::: "memory");
  __syncthreads();
  for (int kt = 0; kt <= thi; ++kt) {
    int cur = kt & 1;
    if (kt < thi) stage_k64(Kpan, kt + 1, Kl[cur ^ 1], tid, w);
    tile_pass1(Kl[cur], qhi0, qhi1, qhi, q0hi, kt, thi, cq, u, rho, ls_hi);
    if (kt <= tlo)
      tile_pass1(Kl[cur], qlo0, qlo1, qlo, q0lo, kt, tlo, cq, u, rho, ls_lo);
    asm volatile("s_waitcnt vmcnt(0)" ::: "memory");
    __syncthreads();
  }
  ls_lo += __shfl_xor(ls_lo, 16);  ls_lo += __shfl_xor(ls_lo, 32);
  ls_hi += __shfl_xor(ls_hi, 16);  ls_hi += __shfl_xor(ls_hi, 32);
  float rl_lo = 1.f / ls_lo, rl_hi = 1.f / ls_hi;

  // ---- pass 2: probs + ctx, shared K/V staging ----
  f32x4 ctx_lo[4] = {}, ctx_hi[4] = {};
  float* apan = attnO + (size_t)bh * 2048 * 2048;
  float* Pw = Pf[w];
  stage_k64(Kpan, 0, Kl[0], tid, w);
  stage_v64(Vpan, 0, Vl[0], tid, w);
  asm volatile("s_waitcnt vmcnt(0)" ::: "memory");
  __syncthreads();
  for (int kt = 0; kt <= thi; ++kt) {
    int cur = kt & 1;
    if (kt < thi) {
      stage_k64(Kpan, kt + 1, Kl[cur ^ 1], tid, w);
      stage_v64(Vpan, kt + 1, Vl[cur ^ 1], tid, w);
    }
    tile_pass2(Kl[cur], Vl[cur], Pw, qhi0, qhi1, qhi, q0hi, kt, thi,
               rl_hi, apan, w, u, cq, rho, sw, ctx_hi);
    if (kt <= tlo)
      tile_pass2(Kl[cur], Vl[cur], Pw, qlo0, qlo1, qlo, q0lo, kt, tlo,
                 rl_lo, apan, w, u, cq, rho, sw, ctx_lo);
    asm volatile("s_waitcnt vmcnt(0)" ::: "memory");
    __syncthreads();
  }

  // masked tails: exact zeros, coalesced (31 zero-tiles per block, uniform)
  f32x4 z4 = {};
  for (int kt = tlo + 1; kt < 32; ++kt)
#pragma unroll
    for (int j = 0; j < 4; ++j)
      *(f32x4*)(apan + (size_t)(q0lo + w*16 + j*4 + u) * 2048 + kt*64 + cq*4) = z4;
  for (int kt = thi + 1; kt < 32; ++kt)
#pragma unroll
    for (int j = 0; j < 4; ++j)
      *(f32x4*)(apan + (size_t)(q0hi + w*16 + j*4 + u) * 2048 + kt*64 + cq*4) = z4;

  // ctx writes: [BS][1024] bf16 for the output GEMM
  int b = bh >> 4, h = bh & 15;
#pragma unroll
  for (int nt = 0; nt < 4; ++nt)
#pragma unroll
    for (int r = 0; r < 4; ++r) {
      int qr = q0lo + w*16 + u*4 + r;
      Ctx[((size_t)b * 2048 + qr) * 1024 + h*64 + nt*16 + cq] = f2bf(ctx_lo[nt][r]);
    }
#pragma unroll
  for (int nt = 0; nt < 4; ++nt)
#pragma unroll
    for (int r = 0; r < 4; ++r) {
      int qr = q0hi + w*16 + u*4 + r;
      Ctx[((size_t)b * 2048 + qr) * 1024 + h*64 + nt*16 + cq] = f2bf(ctx_hi[nt][r]);
    }
}

// ---------------- LayerNorm over 1024 cols ----------------
__global__ __launch_bounds__(256) void ln_kernel(const float* X, const float* g, const float* b, float* out) {
  int row = blockIdx.x, tid = threadIdx.x;
  float4 v = *(const float4*)(X + (size_t)row * 1024 + tid * 4);
  float s  = v.x + v.y + v.z + v.w;
  float q2 = v.x*v.x + v.y*v.y + v.z*v.z + v.w*v.w;
#pragma unroll
  for (int off = 32; off; off >>= 1) { s += __shfl_xor(s, off); q2 += __shfl_xor(q2, off); }
  __shared__ float red[8];
  int w = tid >> 6, lane = tid & 63;
  if (lane == 0) { red[w] = s; red[4 + w] = q2; }
  __syncthreads();
  s  = red[0] + red[1] + red[2] + red[3];
  q2 = red[4] + red[5] + red[6] + red[7];
  float mean = s * (1.f / 1024.f);
  float var  = q2 * (1.f / 1024.f) - mean * mean;
  float rs   = rsqrtf(var + 1e-5f);
  float4 gv = *(const float4*)(g + tid * 4);
  float4 bv = *(const float4*)(b + tid * 4);
  float4 o;
  o.x = (v.x - mean) * rs * gv.x + bv.x;
  o.y = (v.y - mean) * rs * gv.y + bv.y;
  o.z = (v.z - mean) * rs * gv.z + bv.z;
  o.w = (v.w - mean) * rs * gv.w + bv.w;
  *(float4*)(out + (size_t)row * 1024 + tid * 4) = o;
}

extern "C" void kernel_launch(void* const* d_in, const int* in_sizes, int n_in,
                              void* d_out, int out_size, void* d_ws, size_t ws_size,
                              hipStream_t stream) {
  (void)in_sizes; (void)n_in; (void)out_size; (void)ws_size;
  const float* inQ = (const float*)d_in[0];
  const float* inK = (const float*)d_in[1];
  const float* inV = (const float*)d_in[2];
  const float* Wq  = (const float*)d_in[4];
  const float* Wk  = (const float*)d_in[5];
  const float* Wv  = (const float*)d_in[6];
  const float* Wo  = (const float*)d_in[7];
  const float* gam = (const float*)d_in[8];
  const float* bet = (const float*)d_in[9];
  float* out   = (float*)d_out;
  float* attnO = out + (size_t)4194304;

  char* ws = (char*)d_ws;
  u16*   WTo    = (u16*)ws;
  u16*   Qh     = (u16*)(ws + 2097152);
  u16*   Kh     = (u16*)(ws + 2097152 + (size_t)8388608);
  u16*   VhT    = (u16*)(ws + 2097152 + (size_t)2*8388608);
  u16*   Ctx    = (u16*)(ws + 2097152 + (size_t)3*8388608);
  float* OutLin = (float*)(ws + 2097152 + (size_t)4*8388608);

  u16* Xbq = (u16*)attnO;
  u16* Xbk = Xbq + (size_t)4194304;
  u16* Xbv = Xbk + (size_t)4194304;
  u16* WTq = Xbv + (size_t)4194304;
  u16* WTk = WTq + (size_t)1048576;
  u16* WTv = WTk + (size_t)1048576;

  cast_x<<<dim3(4096, 3), 256, 0, stream>>>(inQ, inK, inV, Xbq, Xbk, Xbv);
  trans_w<<<dim3(32, 32, 4), dim3(32, 8), 0, stream>>>(Wq, Wk, Wv, Wo, WTq, WTk, WTv, WTo);
  gemm_qkv<<<dim3(32, 8, 3), 256, 0, stream>>>(Xbq, Xbk, Xbv, WTq, WTk, WTv, Qh, Kh, VhT);
  attn_fused<<<dim3(16, 32), 256, 0, stream>>>(Qh, Kh, VhT, attnO, Ctx);
  gemm_out<<<dim3(32, 8), 256, 0, stream>>>(Ctx, WTo, inQ, OutLin);
  ln_kernel<<<4096, 256, 0, stream>>>(OutLin, gam, bet, out);
}

// Round 4
// 275.557 us; speedup vs baseline: 1.1816x; 1.0491x over previous
//
#include <hip/hip_runtime.h>
#include <stdint.h>

typedef unsigned short u16;
typedef __attribute__((ext_vector_type(8))) short short8;
typedef __attribute__((ext_vector_type(4))) float f32x4;
typedef __attribute__((ext_vector_type(4))) unsigned short u16x4;
typedef __attribute__((ext_vector_type(4))) unsigned int uint4v;

#define MFMA16(a,b,c) __builtin_amdgcn_mfma_f32_16x16x32_bf16((a),(b),(c),0,0,0)

__device__ __forceinline__ void gload16(const void* g, void* l) {
  __builtin_amdgcn_global_load_lds(
      (__attribute__((address_space(1))) void*)(uintptr_t)(g),
      (__attribute__((address_space(3))) void*)(uint32_t)(uintptr_t)(l),
      16, 0, 0);
}

__device__ __forceinline__ u16 f2bf(float x) {
  union { float f; unsigned u; } v; v.f = x;
  unsigned r = v.u + 0x7fffu + ((v.u >> 16) & 1u);
  return (u16)(r >> 16);
}
__device__ __forceinline__ unsigned pack2(float a, float b) {
  return (unsigned)f2bf(a) | ((unsigned)f2bf(b) << 16);
}

// ---------------- cast fp32 -> bf16 for the three inputs ----------------
__global__ __launch_bounds__(256) void cast_x(const float* x0, const float* x1, const float* x2,
                                              u16* y0, u16* y1, u16* y2) {
  const float* x; u16* y;
  if (blockIdx.y == 0)      { x = x0; y = y0; }
  else if (blockIdx.y == 1) { x = x1; y = y1; }
  else                      { x = x2; y = y2; }
  size_t i = ((size_t)blockIdx.x * 256 + threadIdx.x) * 4;
  float4 v = *(const float4*)(x + i);
  u16x4 o; o[0] = f2bf(v.x); o[1] = f2bf(v.y); o[2] = f2bf(v.z); o[3] = f2bf(v.w);
  *(u16x4*)(y + i) = o;
}

// ---------------- transpose + cast weights: WT[n][k] = bf16(W[k][n]) ----------------
__global__ __launch_bounds__(256) void trans_w(const float* w0, const float* w1, const float* w2, const float* w3,
                                               u16* t0, u16* t1, u16* t2, u16* t3) {
  const float* W; u16* T;
  switch (blockIdx.z) {
    case 0:  W = w0; T = t0; break;
    case 1:  W = w1; T = t1; break;
    case 2:  W = w2; T = t2; break;
    default: W = w3; T = t3; break;
  }
  __shared__ float tile[32][33];
  int k0 = blockIdx.x * 32, n0 = blockIdx.y * 32;
  int tx = threadIdx.x, ty = threadIdx.y;
#pragma unroll
  for (int j = 0; j < 4; ++j)
    tile[ty + 8*j][tx] = W[(size_t)(k0 + ty + 8*j) * 1024 + n0 + tx];
  __syncthreads();
#pragma unroll
  for (int j = 0; j < 4; ++j)
    T[(size_t)(n0 + ty + 8*j) * 1024 + k0 + tx] = f2bf(tile[tx][ty + 8*j]);
}

// ---------------- shared GEMM core: C[128x128] = A * WT^T, bf16 MFMA ----------------
__device__ __forceinline__ void gemm_stage(const u16* A, const u16* BT, int row0, int col0,
                                           int tid, int w, int kt, char* la, char* lb) {
#pragma unroll
  for (int j = 0; j < 2; ++j) {
    int c = j * 256 + tid;
    int mr = c & 127, kc = c >> 7;
    gload16(A  + (size_t)(row0 + mr) * 1024 + kt*32 + kc*8, la + (j*4 + w) * 1024);
    gload16(BT + (size_t)(col0 + mr) * 1024 + kt*32 + kc*8, lb + (j*4 + w) * 1024);
  }
}

__device__ __forceinline__ void gemm_core(const u16* A, const u16* BT, int row0, int col0,
                                          char* ldsA, char* ldsB, f32x4 (&acc)[4][4]) {
  int tid = threadIdx.x, w = tid >> 6, lane = tid & 63;
  int u = lane >> 4, c16 = lane & 15, wr = w >> 1, wc = w & 1;
  gemm_stage(A, BT, row0, col0, tid, w, 0, ldsA, ldsB);
  asm volatile("s_waitcnt vmcnt(0)" ::: "memory");
  __syncthreads();
  for (int kt = 0; kt < 32; ++kt) {
    int cur = kt & 1;
    if (kt < 31)
      gemm_stage(A, BT, row0, col0, tid, w, kt + 1, ldsA + (cur^1)*8192, ldsB + (cur^1)*8192);
    const char* la = ldsA + cur * 8192;
    const char* lb = ldsB + cur * 8192;
    short8 af[4], bv[4];
#pragma unroll
    for (int i = 0; i < 4; ++i) {
      af[i] = *(const short8*)(la + (u*128 + wr*64 + i*16 + c16) * 16);
      bv[i] = *(const short8*)(lb + (u*128 + wc*64 + i*16 + c16) * 16);
    }
#pragma unroll
    for (int i = 0; i < 4; ++i)
#pragma unroll
      for (int n = 0; n < 4; ++n)
        acc[i][n] = MFMA16(af[i], bv[n], acc[i][n]);
    asm volatile("s_waitcnt vmcnt(0)" ::: "memory");
    __syncthreads();
  }
}

// ---------------- QKV projections ----------------
__global__ __launch_bounds__(256) void gemm_qkv(const u16* Xq, const u16* Xk, const u16* Xv,
                                                const u16* WTq, const u16* WTk, const u16* WTv,
                                                u16* Qh, u16* Kh, u16* VhT) {
  __shared__ char ldsA[16384], ldsB[16384];
  int z = blockIdx.z;
  const u16* A  = (z == 0) ? Xq  : ((z == 1) ? Xk  : Xv);
  const u16* BT = (z == 0) ? WTq : ((z == 1) ? WTk : WTv);
  int row0 = blockIdx.x * 128, col0 = blockIdx.y * 128;
  f32x4 acc[4][4] = {};
  gemm_core(A, BT, row0, col0, ldsA, ldsB, acc);
  int tid = threadIdx.x, w = tid >> 6, lane = tid & 63, u = lane >> 4, c16 = lane & 15;
  int wr = w >> 1, wc = w & 1;
#pragma unroll
  for (int i = 0; i < 4; ++i)
#pragma unroll
    for (int n = 0; n < 4; ++n)
#pragma unroll
      for (int r = 0; r < 4; ++r) {
        int row = row0 + wr*64 + i*16 + u*4 + r;
        int colg = col0 + wc*64 + n*16 + c16;
        int b = row >> 11, s = row & 2047;
        int h = colg >> 6, d = colg & 63;
        float v = acc[i][n][r];
        if (z == 0)      Qh[((size_t)(b*16 + h) * 2048 + s) * 64 + d] = f2bf(v * 0.125f);
        else if (z == 1) Kh[((size_t)(b*16 + h) * 2048 + s) * 64 + d] = f2bf(v);
        else             VhT[((size_t)(b*16 + h) * 64 + d) * 2048 + s] = f2bf(v);
      }
}

// ---------------- output projection + residual ----------------
__global__ __launch_bounds__(256) void gemm_out(const u16* Ctx, const u16* WTo,
                                                const float* resid, float* outF) {
  __shared__ char ldsA[16384], ldsB[16384];
  int row0 = blockIdx.x * 128, col0 = blockIdx.y * 128;
  f32x4 acc[4][4] = {};
  gemm_core(Ctx, WTo, row0, col0, ldsA, ldsB, acc);
  int tid = threadIdx.x, w = tid >> 6, lane = tid & 63, u = lane >> 4, c16 = lane & 15;
  int wr = w >> 1, wc = w & 1;
#pragma unroll
  for (int i = 0; i < 4; ++i)
#pragma unroll
    for (int n = 0; n < 4; ++n)
#pragma unroll
      for (int r = 0; r < 4; ++r) {
        int row = row0 + wr*64 + i*16 + u*4 + r;
        int colg = col0 + wc*64 + n*16 + c16;
        size_t idx = (size_t)row * 1024 + colg;
        outF[idx] = acc[i][n][r] + resid[idx];
      }
}

// ---------------- fused causal attention (pair-balanced, counted-vmcnt) ----------------
__device__ __forceinline__ void qk_tile(const char* Kbuf, short8 qf0, short8 qf1,
                                        int cq, int u, int rho, f32x4 (&acc)[4]) {
#pragma unroll
  for (int st = 0; st < 4; ++st) {
    short8 a0 = *(const short8*)(Kbuf + (st*16 + cq) * 128 + ((u*16) ^ rho));
    short8 a1 = *(const short8*)(Kbuf + (st*16 + cq) * 128 + ((64 + u*16) ^ rho));
    acc[st] = MFMA16(a0, qf0, acc[st]);
    acc[st] = MFMA16(a1, qf1, acc[st]);
  }
}

__device__ __forceinline__ void stage_k64(const u16* pan, int kt, char* buf, int tid, int w) {
#pragma unroll
  for (int j = 0; j < 2; ++j) {
    int c = j * 256 + tid;
    int row = c >> 3;
    int cc = (c & 7) ^ (row & 7);
    gload16(pan + (size_t)(kt*64 + row) * 64 + cc*8, buf + (j*4 + w) * 1024);
  }
}
__device__ __forceinline__ void stage_v64(const u16* vpan, int kt, char* buf, int tid, int w) {
#pragma unroll
  for (int j = 0; j < 2; ++j) {
    int c = j * 256 + tid;
    int d = c >> 3;
    int cc = (c & 7) ^ (d & 7);
    gload16(vpan + (size_t)d * 2048 + kt*64 + cc*8, buf + (j*4 + w) * 1024);
  }
}

// pass-1 tile: accumulate sum of exp(S) for one q-tile
__device__ __forceinline__ void tile_pass1(const char* Kcur, short8 qf0, short8 qf1,
                                           int q, int q0t, int kt, int ktd_t,
                                           int cq, int u, int rho, float& ls) {
  f32x4 acc[4] = {};
  qk_tile(Kcur, qf0, qf1, cq, u, rho, acc);
  if (kt == ktd_t) {
#pragma unroll
    for (int st = 0; st < 4; ++st)
#pragma unroll
      for (int r = 0; r < 4; ++r) {
        int key = q0t + st*16 + u*4 + r;
        if (key > q) acc[st][r] = -1e30f;
      }
  }
#pragma unroll
  for (int st = 0; st < 4; ++st)
#pragma unroll
    for (int r = 0; r < 4; ++r) ls += __expf(acc[st][r]);
}

// pass-2 tile: probs -> LDS transpose -> coalesced nt store; ctx += P*V
__device__ __forceinline__ void tile_pass2(const char* Kcur, const char* Vcur, float* Pw,
                                           short8 qf0, short8 qf1, int q, int q0t, int kt, int ktd_t,
                                           float rl, float* apan, int w, int u, int cq,
                                           int rho, int sw, f32x4 (&ctx)[4]) {
  f32x4 acc[4] = {};
  qk_tile(Kcur, qf0, qf1, cq, u, rho, acc);
  if (kt == ktd_t) {
#pragma unroll
    for (int st = 0; st < 4; ++st)
#pragma unroll
      for (int r = 0; r < 4; ++r) {
        int key = q0t + st*16 + u*4 + r;
        if (key > q) acc[st][r] = -1e30f;
      }
  }
#pragma unroll
  for (int st = 0; st < 4; ++st) {
    f32x4 p;
#pragma unroll
    for (int r = 0; r < 4; ++r) p[r] = __expf(acc[st][r]) * rl;
    *(f32x4*)&Pw[(cq*64 + st*16 + u*4) ^ sw] = p;
  }
  __builtin_amdgcn_sched_barrier(0);
#pragma unroll
  for (int j = 0; j < 4; ++j) {
    int row = j*4 + u;
    f32x4 v = *(const f32x4*)&Pw[(row*64 + cq*4) ^ ((row & 7) << 2)];
    __builtin_nontemporal_store(v,
        (f32x4*)(apan + (size_t)(q0t + w*16 + row) * 2048 + kt*64 + cq*4));
  }
#pragma unroll
  for (int wd = 0; wd < 2; ++wd) {
    int b0 = (cq*64 + wd*32 + u*8) ^ sw;
    f32x4 pa0 = *(const f32x4*)&Pw[b0];
    f32x4 pa1 = *(const f32x4*)&Pw[b0 ^ 4];
    uint4v pk;
    pk[0] = pack2(pa0[0], pa0[1]);
    pk[1] = pack2(pa0[2], pa0[3]);
    pk[2] = pack2(pa1[0], pa1[1]);
    pk[3] = pack2(pa1[2], pa1[3]);
    union { uint4v u4; short8 s8; } cvt; cvt.u4 = pk;
    short8 pa = cvt.s8;
#pragma unroll
    for (int nt = 0; nt < 4; ++nt) {
      short8 vb = *(const short8*)(Vcur + (nt*16 + cq) * 128 + ((wd*64 + u*16) ^ rho));
      ctx[nt] = MFMA16(pa, vb, ctx[nt]);
    }
  }
  __builtin_amdgcn_sched_barrier(0);
}

__global__ __launch_bounds__(256) void attn_fused(const u16* Qh, const u16* Kh, const u16* VhT,
                                                  float* attnO, u16* Ctx) {
  __shared__ char Kl[2][8192];
  __shared__ char Vl[2][8192];
  __shared__ float Pf[4][1024];     // per-wave 16 q-rows x 64 keys f32, XOR-swizzled words
  int tid = threadIdx.x, w = tid >> 6, lane = tid & 63;
  int u = lane >> 4, cq = lane & 15;
  int pi = blockIdx.x;              // pair index 0..15: tiles pi (lo) and 31-pi (hi)
  int bh = blockIdx.y;
  int tlo = pi, thi = 31 - pi;
  int q0lo = tlo * 64, q0hi = thi * 64;
  int qlo = q0lo + w*16 + cq;
  int qhi = q0hi + w*16 + cq;
  int rho = (cq & 7) << 4;
  int sw  = (cq & 7) << 2;
  const u16* Kpan = Kh  + (size_t)bh * (2048 * 64);
  const u16* Vpan = VhT + (size_t)bh * (64 * 2048);
  const u16* Qlo = Qh + ((size_t)bh * 2048 + qlo) * 64;
  const u16* Qhi = Qh + ((size_t)bh * 2048 + qhi) * 64;
  short8 qlo0 = *(const short8*)(Qlo + u*8);
  short8 qlo1 = *(const short8*)(Qlo + 32 + u*8);
  short8 qhi0 = *(const short8*)(Qhi + u*8);
  short8 qhi1 = *(const short8*)(Qhi + 32 + u*8);

  // ---- pass 1: row sums of exp(S), both tiles share K staging ----
  float ls_lo = 0.f, ls_hi = 0.f;
  stage_k64(Kpan, 0, Kl[0], tid, w);
  asm volatile("s_waitcnt vmcnt(0)" ::: "memory");
  __builtin_amdgcn_s_barrier();
  asm volatile("" ::: "memory");
  for (int kt = 0; kt <= thi; ++kt) {
    int cur = kt & 1;
    if (kt < thi) stage_k64(Kpan, kt + 1, Kl[cur ^ 1], tid, w);
    __builtin_amdgcn_sched_barrier(0);
    tile_pass1(Kl[cur], qhi0, qhi1, qhi, q0hi, kt, thi, cq, u, rho, ls_hi);
    if (kt <= tlo)
      tile_pass1(Kl[cur], qlo0, qlo1, qlo, q0lo, kt, tlo, cq, u, rho, ls_lo);
    if (kt < thi) {
      asm volatile("s_waitcnt vmcnt(0)" ::: "memory");
      __builtin_amdgcn_s_barrier();
      asm volatile("" ::: "memory");
    }
  }
  ls_lo += __shfl_xor(ls_lo, 16);  ls_lo += __shfl_xor(ls_lo, 32);
  ls_hi += __shfl_xor(ls_hi, 16);  ls_hi += __shfl_xor(ls_hi, 32);
  float rl_lo = 1.f / ls_lo, rl_hi = 1.f / ls_hi;

  // handoff: all waves done reading Kl before pass-2 staging overwrites it
  asm volatile("" ::: "memory");
  __builtin_amdgcn_s_barrier();
  asm volatile("" ::: "memory");

  // ---- pass 2: probs + ctx, shared K/V staging; stores ride across barriers ----
  f32x4 ctx_lo[4] = {}, ctx_hi[4] = {};
  float* apan = attnO + (size_t)bh * 2048 * 2048;
  float* Pw = Pf[w];
  stage_k64(Kpan, 0, Kl[0], tid, w);
  stage_v64(Vpan, 0, Vl[0], tid, w);
  asm volatile("s_waitcnt vmcnt(0)" ::: "memory");
  __builtin_amdgcn_s_barrier();
  asm volatile("" ::: "memory");
  for (int kt = 0; kt <= thi; ++kt) {
    int cur = kt & 1;
    if (kt < thi) {
      stage_k64(Kpan, kt + 1, Kl[cur ^ 1], tid, w);
      stage_v64(Vpan, kt + 1, Vl[cur ^ 1], tid, w);
    }
    __builtin_amdgcn_sched_barrier(0);
    tile_pass2(Kl[cur], Vl[cur], Pw, qhi0, qhi1, qhi, q0hi, kt, thi,
               rl_hi, apan, w, u, cq, rho, sw, ctx_hi);
    bool lo_act = (kt <= tlo);
    if (lo_act)
      tile_pass2(Kl[cur], Vl[cur], Pw, qlo0, qlo1, qlo, q0lo, kt, tlo,
                 rl_lo, apan, w, u, cq, rho, sw, ctx_lo);
    if (kt < thi) {
      // loads were issued first: counted wait drains the 4 prefetch loads,
      // leaves this iteration's newest prob stores in flight across the barrier
      if (lo_act) asm volatile("s_waitcnt vmcnt(8)" ::: "memory");
      else        asm volatile("s_waitcnt vmcnt(4)" ::: "memory");
      __builtin_amdgcn_s_barrier();
      asm volatile("" ::: "memory");
    }
  }

  // masked tails: exact zeros, coalesced nt stores
  f32x4 z4 = {};
  for (int kt = tlo + 1; kt < 32; ++kt)
#pragma unroll
    for (int j = 0; j < 4; ++j)
      __builtin_nontemporal_store(z4,
          (f32x4*)(apan + (size_t)(q0lo + w*16 + j*4 + u) * 2048 + kt*64 + cq*4));
  for (int kt = thi + 1; kt < 32; ++kt)
#pragma unroll
    for (int j = 0; j < 4; ++j)
      __builtin_nontemporal_store(z4,
          (f32x4*)(apan + (size_t)(q0hi + w*16 + j*4 + u) * 2048 + kt*64 + cq*4));

  // ctx writes: [BS][1024] bf16 for the output GEMM
  int b = bh >> 4, h = bh & 15;
#pragma unroll
  for (int nt = 0; nt < 4; ++nt)
#pragma unroll
    for (int r = 0; r < 4; ++r) {
      int qr = q0lo + w*16 + u*4 + r;
      Ctx[((size_t)b * 2048 + qr) * 1024 + h*64 + nt*16 + cq] = f2bf(ctx_lo[nt][r]);
    }
#pragma unroll
  for (int nt = 0; nt < 4; ++nt)
#pragma unroll
    for (int r = 0; r < 4; ++r) {
      int qr = q0hi + w*16 + u*4 + r;
      Ctx[((size_t)b * 2048 + qr) * 1024 + h*64 + nt*16 + cq] = f2bf(ctx_hi[nt][r]);
    }
}

// ---------------- LayerNorm over 1024 cols ----------------
__global__ __launch_bounds__(256) void ln_kernel(const float* X, const float* g, const float* b, float* out) {
  int row = blockIdx.x, tid = threadIdx.x;
  float4 v = *(const float4*)(X + (size_t)row * 1024 + tid * 4);
  float s  = v.x + v.y + v.z + v.w;
  float q2 = v.x*v.x + v.y*v.y + v.z*v.z + v.w*v.w;
#pragma unroll
  for (int off = 32; off; off >>= 1) { s += __shfl_xor(s, off); q2 += __shfl_xor(q2, off); }
  __shared__ float red[8];
  int w = tid >> 6, lane = tid & 63;
  if (lane == 0) { red[w] = s; red[4 + w] = q2; }
  __syncthreads();
  s  = red[0] + red[1] + red[2] + red[3];
  q2 = red[4] + red[5] + red[6] + red[7];
  float mean = s * (1.f / 1024.f);
  float var  = q2 * (1.f / 1024.f) - mean * mean;
  float rs   = rsqrtf(var + 1e-5f);
  float4 gv = *(const float4*)(g + tid * 4);
  float4 bv = *(const float4*)(b + tid * 4);
  float4 o;
  o.x = (v.x - mean) * rs * gv.x + bv.x;
  o.y = (v.y - mean) * rs * gv.y + bv.y;
  o.z = (v.z - mean) * rs * gv.z + bv.z;
  o.w = (v.w - mean) * rs * gv.w + bv.w;
  *(float4*)(out + (size_t)row * 1024 + tid * 4) = o;
}

extern "C" void kernel_launch(void* const* d_in, const int* in_sizes, int n_in,
                              void* d_out, int out_size, void* d_ws, size_t ws_size,
                              hipStream_t stream) {
  (void)in_sizes; (void)n_in; (void)out_size; (void)ws_size;
  const float* inQ = (const float*)d_in[0];
  const float* inK = (const float*)d_in[1];
  const float* inV = (const float*)d_in[2];
  const float* Wq  = (const float*)d_in[4];
  const float* Wk  = (const float*)d_in[5];
  const float* Wv  = (const float*)d_in[6];
  const float* Wo  = (const float*)d_in[7];
  const float* gam = (const float*)d_in[8];
  const float* bet = (const float*)d_in[9];
  float* out   = (float*)d_out;
  float* attnO = out + (size_t)4194304;

  char* ws = (char*)d_ws;
  u16*   WTo    = (u16*)ws;
  u16*   Qh     = (u16*)(ws + 2097152);
  u16*   Kh     = (u16*)(ws + 2097152 + (size_t)8388608);
  u16*   VhT    = (u16*)(ws + 2097152 + (size_t)2*8388608);
  u16*   Ctx    = (u16*)(ws + 2097152 + (size_t)3*8388608);
  float* OutLin = (float*)(ws + 2097152 + (size_t)4*8388608);

  u16* Xbq = (u16*)attnO;
  u16* Xbk = Xbq + (size_t)4194304;
  u16* Xbv = Xbk + (size_t)4194304;
  u16* WTq = Xbv + (size_t)4194304;
  u16* WTk = WTq + (size_t)1048576;
  u16* WTv = WTk + (size_t)1048576;

  cast_x<<<dim3(4096, 3), 256, 0, stream>>>(inQ, inK, inV, Xbq, Xbk, Xbv);
  trans_w<<<dim3(32, 32, 4), dim3(32, 8), 0, stream>>>(Wq, Wk, Wv, Wo, WTq, WTk, WTv, WTo);
  gemm_qkv<<<dim3(32, 8, 3), 256, 0, stream>>>(Xbq, Xbk, Xbv, WTq, WTk, WTv, Qh, Kh, VhT);
  attn_fused<<<dim3(16, 32), 256, 0, stream>>>(Qh, Kh, VhT, attnO, Ctx);
  gemm_out<<<dim3(32, 8), 256, 0, stream>>>(Ctx, WTo, inQ, OutLin);
  ln_kernel<<<4096, 256, 0, stream>>>(OutLin, gam, bet, out);
}

// Round 5
// 269.242 us; speedup vs baseline: 1.2094x; 1.0235x over previous
//
#include <hip/hip_runtime.h>
#include <stdint.h>

typedef unsigned short u16;
typedef __attribute__((ext_vector_type(8))) short short8;
typedef __attribute__((ext_vector_type(4))) float f32x4;
typedef __attribute__((ext_vector_type(4))) unsigned short u16x4;
typedef __attribute__((ext_vector_type(4))) unsigned int uint4v;

#define MFMA16(a,b,c) __builtin_amdgcn_mfma_f32_16x16x32_bf16((a),(b),(c),0,0,0)

__device__ __forceinline__ void gload16(const void* g, void* l) {
  __builtin_amdgcn_global_load_lds(
      (__attribute__((address_space(1))) void*)(uintptr_t)(g),
      (__attribute__((address_space(3))) void*)(uint32_t)(uintptr_t)(l),
      16, 0, 0);
}

__device__ __forceinline__ u16 f2bf(float x) {
  union { float f; unsigned u; } v; v.f = x;
  unsigned r = v.u + 0x7fffu + ((v.u >> 16) & 1u);
  return (u16)(r >> 16);
}
__device__ __forceinline__ unsigned pack2(float a, float b) {
  return (unsigned)f2bf(a) | ((unsigned)f2bf(b) << 16);
}

// ---------------- fused prep: cast inputs (z<3) + transpose weights (z>=3) ----------------
__global__ __launch_bounds__(256) void prep_kernel(const float* x0, const float* x1, const float* x2,
                                                   u16* y0, u16* y1, u16* y2,
                                                   const float* w0, const float* w1, const float* w2, const float* w3,
                                                   u16* t0, u16* t1, u16* t2, u16* t3) {
  __shared__ float tile[32][33];
  int z = blockIdx.y;
  if (z < 3) {
    const float* x = (z == 0) ? x0 : ((z == 1) ? x1 : x2);
    u16*         y = (z == 0) ? y0 : ((z == 1) ? y1 : y2);
    size_t i = ((size_t)blockIdx.x * 256 + threadIdx.x) * 4;
    float4 v = *(const float4*)(x + i);
    u16x4 o; o[0] = f2bf(v.x); o[1] = f2bf(v.y); o[2] = f2bf(v.z); o[3] = f2bf(v.w);
    *(u16x4*)(y + i) = o;
  } else {
    if (blockIdx.x >= 1024) return;
    const float* W; u16* T;
    switch (z - 3) {
      case 0:  W = w0; T = t0; break;
      case 1:  W = w1; T = t1; break;
      case 2:  W = w2; T = t2; break;
      default: W = w3; T = t3; break;
    }
    int k0 = (blockIdx.x >> 5) * 32, n0 = (blockIdx.x & 31) * 32;
    int tx = threadIdx.x & 31, ty = threadIdx.x >> 5;
#pragma unroll
    for (int j = 0; j < 4; ++j)
      tile[ty + 8*j][tx] = W[(size_t)(k0 + ty + 8*j) * 1024 + n0 + tx];
    __syncthreads();
#pragma unroll
    for (int j = 0; j < 4; ++j)
      T[(size_t)(n0 + ty + 8*j) * 1024 + k0 + tx] = f2bf(tile[tx][ty + 8*j]);
  }
}

// ---------------- shared GEMM core: C[128x128] = A * WT^T, 3-deep pipelined ----------------
__device__ __forceinline__ void gemm_stage(const u16* A, const u16* BT, int row0, int col0,
                                           int tid, int w, int kt, char* la, char* lb) {
#pragma unroll
  for (int j = 0; j < 2; ++j) {
    int c = j * 256 + tid;
    int mr = c & 127, kc = c >> 7;
    gload16(A  + (size_t)(row0 + mr) * 1024 + kt*32 + kc*8, la + (j*4 + w) * 1024);
    gload16(BT + (size_t)(col0 + mr) * 1024 + kt*32 + kc*8, lb + (j*4 + w) * 1024);
  }
}

__device__ __forceinline__ void gemm_core(const u16* A, const u16* BT, int row0, int col0,
                                          char* ldsA, char* ldsB, f32x4 (&acc)[4][4]) {
  int tid = threadIdx.x, w = tid >> 6, lane = tid & 63;
  int u = lane >> 4, c16 = lane & 15, wr = w >> 1, wc = w & 1;
  gemm_stage(A, BT, row0, col0, tid, w, 0, ldsA, ldsB);
  gemm_stage(A, BT, row0, col0, tid, w, 1, ldsA + 8192, ldsB + 8192);
  int cur = 0;
  for (int kt = 0; kt < 32; ++kt) {
    // drain only tile kt's 4 loads; tiles kt+1 (and kt+2 after staging) stay in flight
    if (kt < 31) asm volatile("s_waitcnt vmcnt(4)" ::: "memory");
    else         asm volatile("s_waitcnt vmcnt(0)" ::: "memory");
    __builtin_amdgcn_s_barrier();
    asm volatile("" ::: "memory");
    if (kt < 30) {
      int nb = cur + 2; if (nb >= 3) nb -= 3;
      gemm_stage(A, BT, row0, col0, tid, w, kt + 2, ldsA + nb*8192, ldsB + nb*8192);
    }
    __builtin_amdgcn_sched_barrier(0);
    const char* la = ldsA + cur * 8192;
    const char* lb = ldsB + cur * 8192;
    short8 af[4], bv[4];
#pragma unroll
    for (int i = 0; i < 4; ++i) {
      af[i] = *(const short8*)(la + (u*128 + wr*64 + i*16 + c16) * 16);
      bv[i] = *(const short8*)(lb + (u*128 + wc*64 + i*16 + c16) * 16);
    }
#pragma unroll
    for (int i = 0; i < 4; ++i)
#pragma unroll
      for (int n = 0; n < 4; ++n)
        acc[i][n] = MFMA16(af[i], bv[n], acc[i][n]);
    cur = cur + 1; if (cur >= 3) cur = 0;
  }
}

// ---------------- QKV projections ----------------
__global__ __launch_bounds__(256) void gemm_qkv(const u16* Xq, const u16* Xk, const u16* Xv,
                                                const u16* WTq, const u16* WTk, const u16* WTv,
                                                u16* Qh, u16* Kh, u16* VhT) {
  __shared__ char ldsA[24576], ldsB[24576];
  int z = blockIdx.z;
  const u16* A  = (z == 0) ? Xq  : ((z == 1) ? Xk  : Xv);
  const u16* BT = (z == 0) ? WTq : ((z == 1) ? WTk : WTv);
  int row0 = blockIdx.x * 128, col0 = blockIdx.y * 128;
  f32x4 acc[4][4] = {};
  gemm_core(A, BT, row0, col0, ldsA, ldsB, acc);
  int tid = threadIdx.x, w = tid >> 6, lane = tid & 63, u = lane >> 4, c16 = lane & 15;
  int wr = w >> 1, wc = w & 1;
#pragma unroll
  for (int i = 0; i < 4; ++i)
#pragma unroll
    for (int n = 0; n < 4; ++n)
#pragma unroll
      for (int r = 0; r < 4; ++r) {
        int row = row0 + wr*64 + i*16 + u*4 + r;
        int colg = col0 + wc*64 + n*16 + c16;
        int b = row >> 11, s = row & 2047;
        int h = colg >> 6, d = colg & 63;
        float v = acc[i][n][r];
        if (z == 0)      Qh[((size_t)(b*16 + h) * 2048 + s) * 64 + d] = f2bf(v * 0.125f);
        else if (z == 1) Kh[((size_t)(b*16 + h) * 2048 + s) * 64 + d] = f2bf(v);
        else             VhT[((size_t)(b*16 + h) * 64 + d) * 2048 + s] = f2bf(v);
      }
}

// ---------------- output projection + residual ----------------
__global__ __launch_bounds__(256) void gemm_out(const u16* Ctx, const u16* WTo,
                                                const float* resid, float* outF) {
  __shared__ char ldsA[24576], ldsB[24576];
  int row0 = blockIdx.x * 128, col0 = blockIdx.y * 128;
  f32x4 acc[4][4] = {};
  gemm_core(Ctx, WTo, row0, col0, ldsA, ldsB, acc);
  int tid = threadIdx.x, w = tid >> 6, lane = tid & 63, u = lane >> 4, c16 = lane & 15;
  int wr = w >> 1, wc = w & 1;
#pragma unroll
  for (int i = 0; i < 4; ++i)
#pragma unroll
    for (int n = 0; n < 4; ++n)
#pragma unroll
      for (int r = 0; r < 4; ++r) {
        int row = row0 + wr*64 + i*16 + u*4 + r;
        int colg = col0 + wc*64 + n*16 + c16;
        size_t idx = (size_t)row * 1024 + colg;
        outF[idx] = acc[i][n][r] + resid[idx];
      }
}

// ---------------- fused causal attention (pair-balanced, counted-vmcnt, setprio) ----------------
__device__ __forceinline__ void qk_tile(const char* Kbuf, short8 qf0, short8 qf1,
                                        int cq, int u, int rho, f32x4 (&acc)[4]) {
#pragma unroll
  for (int st = 0; st < 4; ++st) {
    short8 a0 = *(const short8*)(Kbuf + (st*16 + cq) * 128 + ((u*16) ^ rho));
    short8 a1 = *(const short8*)(Kbuf + (st*16 + cq) * 128 + ((64 + u*16) ^ rho));
    acc[st] = MFMA16(a0, qf0, acc[st]);
    acc[st] = MFMA16(a1, qf1, acc[st]);
  }
}

__device__ __forceinline__ void stage_k64(const u16* pan, int kt, char* buf, int tid, int w) {
#pragma unroll
  for (int j = 0; j < 2; ++j) {
    int c = j * 256 + tid;
    int row = c >> 3;
    int cc = (c & 7) ^ (row & 7);
    gload16(pan + (size_t)(kt*64 + row) * 64 + cc*8, buf + (j*4 + w) * 1024);
  }
}
__device__ __forceinline__ void stage_v64(const u16* vpan, int kt, char* buf, int tid, int w) {
#pragma unroll
  for (int j = 0; j < 2; ++j) {
    int c = j * 256 + tid;
    int d = c >> 3;
    int cc = (c & 7) ^ (d & 7);
    gload16(vpan + (size_t)d * 2048 + kt*64 + cc*8, buf + (j*4 + w) * 1024);
  }
}

// pass-1 tile: accumulate sum of exp(S) for one q-tile
__device__ __forceinline__ void tile_pass1(const char* Kcur, short8 qf0, short8 qf1,
                                           int q, int q0t, int kt, int ktd_t,
                                           int cq, int u, int rho, float& ls) {
  f32x4 acc[4] = {};
  qk_tile(Kcur, qf0, qf1, cq, u, rho, acc);
  if (kt == ktd_t) {
#pragma unroll
    for (int st = 0; st < 4; ++st)
#pragma unroll
      for (int r = 0; r < 4; ++r) {
        int key = q0t + st*16 + u*4 + r;
        if (key > q) acc[st][r] = -1e30f;
      }
  }
#pragma unroll
  for (int st = 0; st < 4; ++st)
#pragma unroll
    for (int r = 0; r < 4; ++r) ls += __expf(acc[st][r]);
}

// pass-2 tile: probs -> LDS transpose -> coalesced nt store; ctx += P*V
__device__ __forceinline__ void tile_pass2(const char* Kcur, const char* Vcur, float* Pw,
                                           short8 qf0, short8 qf1, int q, int q0t, int kt, int ktd_t,
                                           float rl, float* apan, int w, int u, int cq,
                                           int rho, int sw, f32x4 (&ctx)[4]) {
  f32x4 acc[4] = {};
  __builtin_amdgcn_s_setprio(1);
  qk_tile(Kcur, qf0, qf1, cq, u, rho, acc);
  if (kt == ktd_t) {
#pragma unroll
    for (int st = 0; st < 4; ++st)
#pragma unroll
      for (int r = 0; r < 4; ++r) {
        int key = q0t + st*16 + u*4 + r;
        if (key > q) acc[st][r] = -1e30f;
      }
  }
#pragma unroll
  for (int st = 0; st < 4; ++st) {
    f32x4 p;
#pragma unroll
    for (int r = 0; r < 4; ++r) p[r] = __expf(acc[st][r]) * rl;
    *(f32x4*)&Pw[(cq*64 + st*16 + u*4) ^ sw] = p;
  }
  __builtin_amdgcn_sched_barrier(0);
#pragma unroll
  for (int j = 0; j < 4; ++j) {
    int row = j*4 + u;
    f32x4 v = *(const f32x4*)&Pw[(row*64 + cq*4) ^ ((row & 7) << 2)];
    __builtin_nontemporal_store(v,
        (f32x4*)(apan + (size_t)(q0t + w*16 + row) * 2048 + kt*64 + cq*4));
  }
#pragma unroll
  for (int wd = 0; wd < 2; ++wd) {
    int b0 = (cq*64 + wd*32 + u*8) ^ sw;
    f32x4 pa0 = *(const f32x4*)&Pw[b0];
    f32x4 pa1 = *(const f32x4*)&Pw[b0 ^ 4];
    uint4v pk;
    pk[0] = pack2(pa0[0], pa0[1]);
    pk[1] = pack2(pa0[2], pa0[3]);
    pk[2] = pack2(pa1[0], pa1[1]);
    pk[3] = pack2(pa1[2], pa1[3]);
    union { uint4v u4; short8 s8; } cvt; cvt.u4 = pk;
    short8 pa = cvt.s8;
#pragma unroll
    for (int nt = 0; nt < 4; ++nt) {
      short8 vb = *(const short8*)(Vcur + (nt*16 + cq) * 128 + ((wd*64 + u*16) ^ rho));
      ctx[nt] = MFMA16(pa, vb, ctx[nt]);
    }
  }
  __builtin_amdgcn_s_setprio(0);
  __builtin_amdgcn_sched_barrier(0);
}

__global__ __launch_bounds__(256) void attn_fused(const u16* Qh, const u16* Kh, const u16* VhT,
                                                  float* attnO, u16* Ctx) {
  __shared__ char Kl[3][8192];
  __shared__ char Vl[2][8192];
  __shared__ float Pf[4][1024];     // per-wave 16 q-rows x 64 keys f32, XOR-swizzled words
  int tid = threadIdx.x, w = tid >> 6, lane = tid & 63;
  int u = lane >> 4, cq = lane & 15;
  int pi = blockIdx.x;              // pair index 0..15: tiles pi (lo) and 31-pi (hi)
  int bh = blockIdx.y;
  int tlo = pi, thi = 31 - pi;
  int q0lo = tlo * 64, q0hi = thi * 64;
  int qlo = q0lo + w*16 + cq;
  int qhi = q0hi + w*16 + cq;
  int rho = (cq & 7) << 4;
  int sw  = (cq & 7) << 2;
  const u16* Kpan = Kh  + (size_t)bh * (2048 * 64);
  const u16* Vpan = VhT + (size_t)bh * (64 * 2048);
  const u16* Qlo = Qh + ((size_t)bh * 2048 + qlo) * 64;
  const u16* Qhi = Qh + ((size_t)bh * 2048 + qhi) * 64;
  short8 qlo0 = *(const short8*)(Qlo + u*8);
  short8 qlo1 = *(const short8*)(Qlo + 32 + u*8);
  short8 qhi0 = *(const short8*)(Qhi + u*8);
  short8 qhi1 = *(const short8*)(Qhi + 32 + u*8);

  // ---- pass 1: row sums of exp(S), 3-deep K prefetch ----
  float ls_lo = 0.f, ls_hi = 0.f;
  stage_k64(Kpan, 0, Kl[0], tid, w);
  stage_k64(Kpan, 1, Kl[1], tid, w);
  int cur1 = 0;
  for (int kt = 0; kt <= thi; ++kt) {
    if (kt < thi) asm volatile("s_waitcnt vmcnt(4)" ::: "memory");
    else          asm volatile("s_waitcnt vmcnt(0)" ::: "memory");
    __builtin_amdgcn_s_barrier();
    asm volatile("" ::: "memory");
    if (kt + 2 <= thi) {
      int nb = cur1 + 2; if (nb >= 3) nb -= 3;
      stage_k64(Kpan, kt + 2, Kl[nb], tid, w);
    }
    __builtin_amdgcn_sched_barrier(0);
    __builtin_amdgcn_s_setprio(1);
    tile_pass1(Kl[cur1], qhi0, qhi1, qhi, q0hi, kt, thi, cq, u, rho, ls_hi);
    if (kt <= tlo)
      tile_pass1(Kl[cur1], qlo0, qlo1, qlo, q0lo, kt, tlo, cq, u, rho, ls_lo);
    __builtin_amdgcn_s_setprio(0);
    cur1 = cur1 + 1; if (cur1 >= 3) cur1 = 0;
  }
  ls_lo += __shfl_xor(ls_lo, 16);  ls_lo += __shfl_xor(ls_lo, 32);
  ls_hi += __shfl_xor(ls_hi, 16);  ls_hi += __shfl_xor(ls_hi, 32);
  float rl_lo = 1.f / ls_lo, rl_hi = 1.f / ls_hi;

  // handoff: all waves done reading Kl before pass-2 staging overwrites it
  asm volatile("" ::: "memory");
  __builtin_amdgcn_s_barrier();
  asm volatile("" ::: "memory");

  // ---- pass 2: probs + ctx, shared K/V staging; stores ride across barriers ----
  f32x4 ctx_lo[4] = {}, ctx_hi[4] = {};
  float* apan = attnO + (size_t)bh * 2048 * 2048;
  float* Pw = Pf[w];
  stage_k64(Kpan, 0, Kl[0], tid, w);
  stage_v64(Vpan, 0, Vl[0], tid, w);
  asm volatile("s_waitcnt vmcnt(0)" ::: "memory");
  __builtin_amdgcn_s_barrier();
  asm volatile("" ::: "memory");
  for (int kt = 0; kt <= thi; ++kt) {
    int cur = kt & 1;
    if (kt < thi) {
      stage_k64(Kpan, kt + 1, Kl[cur ^ 1], tid, w);
      stage_v64(Vpan, kt + 1, Vl[cur ^ 1], tid, w);
    }
    __builtin_amdgcn_sched_barrier(0);
    tile_pass2(Kl[cur], Vl[cur], Pw, qhi0, qhi1, qhi, q0hi, kt, thi,
               rl_hi, apan, w, u, cq, rho, sw, ctx_hi);
    bool lo_act = (kt <= tlo);
    if (lo_act)
      tile_pass2(Kl[cur], Vl[cur], Pw, qlo0, qlo1, qlo, q0lo, kt, tlo,
                 rl_lo, apan, w, u, cq, rho, sw, ctx_lo);
    if (kt < thi) {
      // loads were issued first: counted wait drains the 8 prefetch loads,
      // leaves this iteration's prob stores in flight across the barrier
      if (lo_act) asm volatile("s_waitcnt vmcnt(8)" ::: "memory");
      else        asm volatile("s_waitcnt vmcnt(4)" ::: "memory");
      __builtin_amdgcn_s_barrier();
      asm volatile("" ::: "memory");
    }
  }

  // masked tails: exact zeros, coalesced nt stores
  f32x4 z4 = {};
  for (int kt = tlo + 1; kt < 32; ++kt)
#pragma unroll
    for (int j = 0; j < 4; ++j)
      __builtin_nontemporal_store(z4,
          (f32x4*)(apan + (size_t)(q0lo + w*16 + j*4 + u) * 2048 + kt*64 + cq*4));
  for (int kt = thi + 1; kt < 32; ++kt)
#pragma unroll
    for (int j = 0; j < 4; ++j)
      __builtin_nontemporal_store(z4,
          (f32x4*)(apan + (size_t)(q0hi + w*16 + j*4 + u) * 2048 + kt*64 + cq*4));

  // ctx writes: [BS][1024] bf16 for the output GEMM
  int b = bh >> 4, h = bh & 15;
#pragma unroll
  for (int nt = 0; nt < 4; ++nt)
#pragma unroll
    for (int r = 0; r < 4; ++r) {
      int qr = q0lo + w*16 + u*4 + r;
      Ctx[((size_t)b * 2048 + qr) * 1024 + h*64 + nt*16 + cq] = f2bf(ctx_lo[nt][r]);
    }
#pragma unroll
  for (int nt = 0; nt < 4; ++nt)
#pragma unroll
    for (int r = 0; r < 4; ++r) {
      int qr = q0hi + w*16 + u*4 + r;
      Ctx[((size_t)b * 2048 + qr) * 1024 + h*64 + nt*16 + cq] = f2bf(ctx_hi[nt][r]);
    }
}

// ---------------- LayerNorm over 1024 cols ----------------
__global__ __launch_bounds__(256) void ln_kernel(const float* X, const float* g, const float* b, float* out) {
  int row = blockIdx.x, tid = threadIdx.x;
  float4 v = *(const float4*)(X + (size_t)row * 1024 + tid * 4);
  float s  = v.x + v.y + v.z + v.w;
  float q2 = v.x*v.x + v.y*v.y + v.z*v.z + v.w*v.w;
#pragma unroll
  for (int off = 32; off; off >>= 1) { s += __shfl_xor(s, off); q2 += __shfl_xor(q2, off); }
  __shared__ float red[8];
  int w = tid >> 6, lane = tid & 63;
  if (lane == 0) { red[w] = s; red[4 + w] = q2; }
  __syncthreads();
  s  = red[0] + red[1] + red[2] + red[3];
  q2 = red[4] + red[5] + red[6] + red[7];
  float mean = s * (1.f / 1024.f);
  float var  = q2 * (1.f / 1024.f) - mean * mean;
  float rs   = rsqrtf(var + 1e-5f);
  float4 gv = *(const float4*)(g + tid * 4);
  float4 bv = *(const float4*)(b + tid * 4);
  float4 o;
  o.x = (v.x - mean) * rs * gv.x + bv.x;
  o.y = (v.y - mean) * rs * gv.y + bv.y;
  o.z = (v.z - mean) * rs * gv.z + bv.z;
  o.w = (v.w - mean) * rs * gv.w + bv.w;
  *(float4*)(out + (size_t)row * 1024 + tid * 4) = o;
}

extern "C" void kernel_launch(void* const* d_in, const int* in_sizes, int n_in,
                              void* d_out, int out_size, void* d_ws, size_t ws_size,
                              hipStream_t stream) {
  (void)in_sizes; (void)n_in; (void)out_size; (void)ws_size;
  const float* inQ = (const float*)d_in[0];
  const float* inK = (const float*)d_in[1];
  const float* inV = (const float*)d_in[2];
  const float* Wq  = (const float*)d_in[4];
  const float* Wk  = (const float*)d_in[5];
  const float* Wv  = (const float*)d_in[6];
  const float* Wo  = (const float*)d_in[7];
  const float* gam = (const float*)d_in[8];
  const float* bet = (const float*)d_in[9];
  float* out   = (float*)d_out;
  float* attnO = out + (size_t)4194304;

  char* ws = (char*)d_ws;
  u16*   WTo    = (u16*)ws;
  u16*   Qh     = (u16*)(ws + 2097152);
  u16*   Kh     = (u16*)(ws + 2097152 + (size_t)8388608);
  u16*   VhT    = (u16*)(ws + 2097152 + (size_t)2*8388608);
  u16*   Ctx    = (u16*)(ws + 2097152 + (size_t)3*8388608);
  float* OutLin = (float*)(ws + 2097152 + (size_t)4*8388608);

  u16* Xbq = (u16*)attnO;
  u16* Xbk = Xbq + (size_t)4194304;
  u16* Xbv = Xbk + (size_t)4194304;
  u16* WTq = Xbv + (size_t)4194304;
  u16* WTk = WTq + (size_t)1048576;
  u16* WTv = WTk + (size_t)1048576;

  prep_kernel<<<dim3(4096, 7), 256, 0, stream>>>(inQ, inK, inV, Xbq, Xbk, Xbv,
                                                 Wq, Wk, Wv, Wo, WTq, WTk, WTv, WTo);
  gemm_qkv<<<dim3(32, 8, 3), 256, 0, stream>>>(Xbq, Xbk, Xbv, WTq, WTk, WTv, Qh, Kh, VhT);
  attn_fused<<<dim3(16, 32), 256, 0, stream>>>(Qh, Kh, VhT, attnO, Ctx);
  gemm_out<<<dim3(32, 8), 256, 0, stream>>>(Ctx, WTo, inQ, OutLin);
  ln_kernel<<<4096, 256, 0, stream>>>(OutLin, gam, bet, out);
}